// Round 6
// baseline (77.808 us; speedup 1.0000x reference)
//
#include <hip/hip_runtime.h>

typedef _Float16 half_t;
typedef _Float16 f16x4 __attribute__((ext_vector_type(4)));
typedef _Float16 f16x8 __attribute__((ext_vector_type(8)));
typedef float f32x16 __attribute__((ext_vector_type(16)));

#define BATCH 4
#define NPTS 8192
#define QSEG 128                      // queries per block (4 waves x 32)
#define CHUNK 1024                    // candidates staged per LDS chunk
#define NTILES 32                     // 32-wide candidate tiles per chunk
#define NCH (NPTS / CHUNK)            // 8 chunks -> all candidates per block

// K=7 embedding in one 32x32x8 MFMA -> complete squared-distance tile:
// A row (query q):     k0..3 = [qx, qy, qz, qhi]   k4..6 = [qlo, 1, 1]
// B col (candidate c): k0..3 = [-2cx,-2cy,-2cz, 1] k4..6 = [1, chi, clo]
// dot = -2 q.c + ||q||^2 + ||c||^2   (coords f16-quantized, norms hi/lo f16)
#if __has_builtin(__builtin_amdgcn_mfma_f32_32x32x8f16)
static __device__ __forceinline__ f32x16 MFMA8(f16x4 a, f16x4 b, f32x16 c) {
    return __builtin_amdgcn_mfma_f32_32x32x8f16(a, b, c, 0, 0, 0);
}
#else
// fallback: same k-permutation applied to both operands -> identical dot
static __device__ __forceinline__ f32x16 MFMA8(f16x4 a, f16x4 b, f32x16 c) {
    f16x8 a8 = {a[0], a[1], a[2], a[3], (half_t)0.f, (half_t)0.f, (half_t)0.f, (half_t)0.f};
    f16x8 b8 = {b[0], b[1], b[2], b[3], (half_t)0.f, (half_t)0.f, (half_t)0.f, (half_t)0.f};
    return __builtin_amdgcn_mfma_f32_32x32x16_f16(a8, b8, c, 0, 0, 0);
}
#endif

// dir 0: queries = rec (per-m min over n -> loss_1), candidates = gt
// dir 1: queries = gt  (per-n min over m -> loss_2), candidates = rec
__global__ __launch_bounds__(256, 2) void chamfer_kernel(
    const float* __restrict__ gt, const float* __restrict__ rec,
    float* __restrict__ out)
{
    const int qseg = blockIdx.x;   // 0..63
    const int b    = blockIdx.y;   // 0..3
    const int dir  = blockIdx.z;   // 0..1
    const float* Q = (dir == 0) ? rec : gt;
    const float* C = (dir == 0) ? gt  : rec;
    Q += (size_t)b * NPTS * 3;
    C += (size_t)b * NPTS * 3;

    const int tid  = threadIdx.x;
    const int lane = tid & 63;
    const int w    = tid >> 6;
    const int lr   = lane & 31;
    const int lh   = lane >> 5;

    __shared__ float2 bfrag[NTILES][64];   // 16 KB packed B fragments (8B/lane)
    __shared__ float  wsum[4];

    // A fragment: wave w owns queries [qseg*QSEG + w*32, +32). row=lr, k=lh*4+e
    f16x4 afrag;
    {
        int q = qseg * QSEG + w * 32 + lr;
        float qx = Q[q*3+0], qy = Q[q*3+1], qz = Q[q*3+2];
        half_t hx = (half_t)qx, hy = (half_t)qy, hz = (half_t)qz;
        float fx = (float)hx, fy = (float)hy, fz = (float)hz;
        float nrm = fx*fx + fy*fy + fz*fz;
        half_t nhi = (half_t)nrm;
        half_t nlo = (half_t)(nrm - (float)nhi);
        if (lh == 0) { afrag[0]=hx;  afrag[1]=hy;          afrag[2]=hz;          afrag[3]=nhi; }
        else         { afrag[0]=nlo; afrag[1]=(half_t)1.f; afrag[2]=(half_t)1.f; afrag[3]=(half_t)0.f; }
    }

    f32x16 colacc;
    #pragma unroll
    for (int i = 0; i < 16; ++i) colacc[i] = 3.0e38f;
    const f32x16 zc = {};

    // T14 async-stage: prefetch 4 candidate points (6 float2) into regs early
    float2 pref[6];
    auto loadpts = [&](int ch) {
        int m = ch * CHUNK + tid * 4;                  // multiple of 4 -> m*3 even
        const float2* p = (const float2*)C + (size_t)(m * 3) / 2;
        #pragma unroll
        for (int k = 0; k < 6; ++k) pref[k] = p[k];
    };
    auto writepack = [&]() {
        float px[4], py[4], pz[4];
        px[0]=pref[0].x; py[0]=pref[0].y; pz[0]=pref[1].x;
        px[1]=pref[1].y; py[1]=pref[2].x; pz[1]=pref[2].y;
        px[2]=pref[3].x; py[2]=pref[3].y; pz[2]=pref[4].x;
        px[3]=pref[4].y; py[3]=pref[5].x; pz[3]=pref[5].y;
        #pragma unroll
        for (int s = 0; s < 4; ++s) {
            int j = tid * 4 + s;
            half_t hx = (half_t)px[s], hy = (half_t)py[s], hz = (half_t)pz[s];
            float fx = (float)hx, fy = (float)hy, fz = (float)hz;
            float nrm = fx*fx + fy*fy + fz*fz;
            half_t mhi = (half_t)nrm;
            half_t mlo = (half_t)(nrm - (float)mhi);
            union { half_t h[4]; float2 f; } u0, u1;
            u0.h[0] = (half_t)(-2.f*fx); u0.h[1] = (half_t)(-2.f*fy);
            u0.h[2] = (half_t)(-2.f*fz); u0.h[3] = (half_t)1.f;
            u1.h[0] = (half_t)1.f; u1.h[1] = mhi; u1.h[2] = mlo; u1.h[3] = (half_t)0.f;
            int t = j >> 5, c = j & 31;
            bfrag[t][c]      = u0.f;   // lanes 0..31  (k=0..3)
            bfrag[t][c + 32] = u1.f;   // lanes 32..63 (k=4..7)
        }
    };

    union { float2 f; f16x4 h; } cv;

    loadpts(0);
    for (int ch = 0; ch < NCH; ++ch) {
        __syncthreads();              // prior chunk's LDS reads done
        writepack();
        __syncthreads();
        if (ch + 1 < NCH) loadpts(ch + 1);   // issue early, hide under MFMAs

        cv.f = bfrag[0][lane]; f16x4 b0 = cv.h;
        cv.f = bfrag[1][lane]; f16x4 b1 = cv.h;
        f32x16 d0 = MFMA8(afrag, b0, zc);
        f32x16 d1 = MFMA8(afrag, b1, zc);
        #pragma unroll
        for (int t = 2; t < NTILES; t += 2) {
            cv.f = bfrag[t][lane];     f16x4 ba = cv.h;
            cv.f = bfrag[t + 1][lane]; f16x4 bb = cv.h;
            f32x16 na = MFMA8(afrag, ba, zc);
            f32x16 nb = MFMA8(afrag, bb, zc);
            #pragma unroll
            for (int i = 0; i < 16; ++i)
                colacc[i] = fminf(fminf(colacc[i], d0[i]), d1[i]);   // v_min3
            d0 = na; d1 = nb;
        }
        #pragma unroll
        for (int i = 0; i < 16; ++i)
            colacc[i] = fminf(fminf(colacc[i], d0[i]), d1[i]);
    }

    // butterfly min across the 32 cols in each half-wave: every lane gets
    // the full per-query min (query identity = reg/row, mapping irrelevant
    // for the sum)
    float s = 0.0f;
    #pragma unroll
    for (int i = 0; i < 16; ++i) {
        float v = colacc[i];
        v = fminf(v, __shfl_xor(v, 1));
        v = fminf(v, __shfl_xor(v, 2));
        v = fminf(v, __shfl_xor(v, 4));
        v = fminf(v, __shfl_xor(v, 8));
        v = fminf(v, __shfl_xor(v, 16));
        s += fmaxf(v, 1e-10f);        // clamp then accumulate
    }
    // s identical across each 32-lane group; add the two halves
    s += __shfl_xor(s, 32);           // now s = wave's 32-query clamped-min sum
    if (lane == 0) wsum[w] = s;
    __syncthreads();
    if (tid == 0) {
        float tot = wsum[0] + wsum[1] + wsum[2] + wsum[3];
        atomicAdd(out, tot * (1000.0f / 32768.0f));
    }
}

extern "C" void kernel_launch(void* const* d_in, const int* in_sizes, int n_in,
                              void* d_out, int out_size, void* d_ws, size_t ws_size,
                              hipStream_t stream) {
    const float* gt  = (const float*)d_in[0];
    const float* rec = (const float*)d_in[1];
    (void)d_ws; (void)ws_size;

    hipMemsetAsync(d_out, 0, sizeof(float), stream);

    dim3 grid(NPTS / QSEG, BATCH, 2);   // 64 x 4 x 2 = 512 blocks
    chamfer_kernel<<<grid, 256, 0, stream>>>(gt, rec, (float*)d_out);
}